// Round 5
// baseline (218.877 us; speedup 1.0000x reference)
//
#include <hip/hip_runtime.h>

#define T_DIM 512
#define B_DIM 8192
#define NCH   64                 // time chunks
#define LT    8                  // timesteps per chunk (NCH*LT == T_DIM)
#define CG    64                 // columns per wave (one per lane)
#define NCG   (B_DIM / CG)       // 128 column groups
#define WPB   8                  // waves per block
#define K_BLOCK (WPB * 64)       // 512 threads
#define K_GRID  ((NCH * NCG) / WPB)  // 1024 blocks -> 4 blocks/CU, 32 waves/CU
#define GAMMA 0.99f

// Workspace layout (6 MB + 12 B):
//   SM  : float2[NCH][B_DIM]  chunk affine composites      @ 0        (4 MB)
//   CIN : float [NCH][B_DIM]  carry entering each chunk    @ 4 MB     (2 MB)
//   ACC : float[2] + uint ticket                           @ 6 MB
#define SM_OFF  0
#define CIN_OFF ((size_t)NCH * B_DIM * sizeof(float2))
#define ACC_OFF (CIN_OFF + (size_t)NCH * B_DIM * sizeof(float))

// Identities (RHO_THRESHOLD == C_THRESHOLD == 1):
//   ratio = (p_a * sum_q) / (sum_p * q_a)         [no log/exp]
//   m = gamma*rho*(1-done), s = v + rho*(r - v)
//   vtrace_t = s_t + m_t*carry ; adv_t = vtrace_t - v_t ; critic = 0.5*mean(adv^2)
//   next_v cancels except the t=T-1 scan init.
// History: per-t state in registers -> scratch spills (R1/R2); in LDS ->
// 1 block/CU + serial-scan stall (R3); R4's recompute pipeline was right but
// launched only 8 waves/CU (Occupancy 17%) -> latency-bound at 1.5 TB/s.
// This round: NCH=64/LT=8 -> 8192 waves = 32 waves/CU.

__device__ __forceinline__ void eval_t(const float2 pr, const float2 qr,
                                       const float vv, const float rr,
                                       const int a, const int d,
                                       float& ratio, float& m, float& s) {
    float pa = a ? pr.y : pr.x;
    float qa = a ? qr.y : qr.x;
    ratio = (pa * (qr.x + qr.y)) / ((pr.x + pr.y) * qa);
    float rho = fminf(ratio, 1.0f);
    m = d ? 0.0f : GAMMA * rho;
    s = fmaf(rho, rr - vv, vv);
}

__launch_bounds__(K_BLOCK, 8)
__global__ void k_comp(const float* __restrict__ prob,
                       const float* __restrict__ aprob,
                       const float* __restrict__ v,
                       const float* __restrict__ rw,
                       const int* __restrict__ act,
                       const int* __restrict__ dnn,
                       float2* __restrict__ SM) {
    const int lane = threadIdx.x & 63;
    const int gw   = blockIdx.x * WPB + (threadIdx.x >> 6);
    const int cg   = gw & (NCG - 1);
    const int ch   = gw >> 7;               // NCG == 128
    const int col  = cg * CG + lane;
    const int t0   = ch * LT;

    const float2* __restrict__ prob2  = (const float2*)prob;
    const float2* __restrict__ aprob2 = (const float2*)aprob;

    float S = 0.0f, M = 1.0f;
#pragma unroll
    for (int i = LT - 1; i >= 0; --i) {
        const int idx = (t0 + i) * B_DIM + col;
        float ratio, m, s;
        eval_t(prob2[idx], aprob2[idx], v[idx], rw[idx], act[idx], dnn[idx],
               ratio, m, s);
        S = fmaf(m, S, s);                  // compose F_t in front
        M *= m;
    }
    SM[ch * B_DIM + col] = make_float2(S, M);
}

__global__ void k_scan(const float2* __restrict__ SM,
                       const float* __restrict__ nv,
                       float* __restrict__ CIN) {
    const int col = blockIdx.x * blockDim.x + threadIdx.x;   // 8192 threads
    float carry = nv[(T_DIM - 1) * B_DIM + col];
#pragma unroll 16
    for (int ch = NCH - 1; ch >= 0; --ch) {
        float2 sm = SM[ch * B_DIM + col];   // address-independent loads
        CIN[ch * B_DIM + col] = carry;
        carry = fmaf(sm.y, carry, sm.x);
    }
}

__launch_bounds__(K_BLOCK, 8)
__global__ void k_replay(const float* __restrict__ prob,
                         const float* __restrict__ aprob,
                         const float* __restrict__ v,
                         const float* __restrict__ rw,
                         const int* __restrict__ act,
                         const int* __restrict__ dnn,
                         const float* __restrict__ CIN,
                         float* __restrict__ ACC,
                         float* __restrict__ out) {
    __shared__ float red[2 * WPB];
    const int lane = threadIdx.x & 63;
    const int wv   = threadIdx.x >> 6;
    const int gw   = blockIdx.x * WPB + wv;
    const int cg   = gw & (NCG - 1);
    const int ch   = gw >> 7;
    const int col  = cg * CG + lane;
    const int t0   = ch * LT;

    const float2* __restrict__ prob2  = (const float2*)prob;
    const float2* __restrict__ aprob2 = (const float2*)aprob;

    float carry  = CIN[ch * B_DIM + col];
    float critic = 0.0f, msum = 0.0f;
#pragma unroll
    for (int i = LT - 1; i >= 0; --i) {
        const int idx = (t0 + i) * B_DIM + col;
        float vv = v[idx];
        float ratio, m, s;
        eval_t(prob2[idx], aprob2[idx], vv, rw[idx], act[idx], dnn[idx],
               ratio, m, s);
        float u   = fmaf(m, carry, s);       // vtrace_t
        float adv = u - vv;
        carry     = u;
        critic = fmaf(adv, adv, critic);
        float rc = fminf(fmaxf(ratio, 0.8f), 1.2f);
        msum += fminf(ratio * adv, rc * adv);
    }

    // wave reduce, then cross-wave via LDS
#pragma unroll
    for (int off = 32; off > 0; off >>= 1) {
        critic += __shfl_down(critic, off, 64);
        msum   += __shfl_down(msum, off, 64);
    }
    if (lane == 0) { red[wv] = critic; red[WPB + wv] = msum; }
    __syncthreads();
    if (threadIdx.x == 0) {
        float cs = 0.0f, ms = 0.0f;
#pragma unroll
        for (int w = 0; w < WPB; ++w) { cs += red[w]; ms += red[WPB + w]; }
        atomicAdd(&ACC[0], cs);
        atomicAdd(&ACC[1], ms);
        __threadfence();
        unsigned* cnt = (unsigned*)(ACC + 2);
        if (atomicAdd(cnt, 1u) == K_GRID - 1) {
            __threadfence();
            float c_tot = atomicAdd(&ACC[0], 0.0f);
            float m_tot = atomicAdd(&ACC[1], 0.0f);
            const float invN = 1.0f / (float)((size_t)T_DIM * B_DIM);
            out[0] = 0.5f * c_tot * invN - m_tot * invN;
        }
    }
}

extern "C" void kernel_launch(void* const* d_in, const int* in_sizes, int n_in,
                              void* d_out, int out_size, void* d_ws, size_t ws_size,
                              hipStream_t stream) {
    const float* prob  = (const float*)d_in[0];
    const float* aprob = (const float*)d_in[1];
    const float* v     = (const float*)d_in[2];
    const float* nv    = (const float*)d_in[3];
    const float* rw    = (const float*)d_in[4];
    const int*   act   = (const int*)d_in[5];
    const int*   dnn   = (const int*)d_in[6];

    float2* SM  = (float2*)((char*)d_ws + SM_OFF);
    float*  CIN = (float*)((char*)d_ws + CIN_OFF);
    float*  ACC = (float*)((char*)d_ws + ACC_OFF);
    float*  out = (float*)d_out;

    hipMemsetAsync(ACC, 0, 12, stream);
    k_comp<<<K_GRID, K_BLOCK, 0, stream>>>(prob, aprob, v, rw, act, dnn, SM);
    k_scan<<<B_DIM / 256, 256, 0, stream>>>(SM, nv, CIN);
    k_replay<<<K_GRID, K_BLOCK, 0, stream>>>(prob, aprob, v, rw, act, dnn,
                                             CIN, ACC, out);
}